// Round 7
// baseline (232.243 us; speedup 1.0000x reference)
//
#include <hip/hip_runtime.h>

// Problem constants: B=2, T=1024, C=1024, H=16, D=64, K=C=1024.
#define T_DIM 1024
#define C_DIM 1024
#define H_DIM 16
#define D_DIM 64
#define KD    1024

#define NEG_BIG (-1e30f)

typedef short  short8  __attribute__((ext_vector_type(8)));
typedef short  short4v __attribute__((ext_vector_type(4)));
typedef float  f32x4   __attribute__((ext_vector_type(4)));

__device__ __forceinline__ float bf2f(short s) {
  return __uint_as_float(((unsigned)(unsigned short)s) << 16);
}
__device__ __forceinline__ short f2bf(float f) {
  unsigned u = __float_as_uint(f);
  u += 0x7fffu + ((u >> 16) & 1u);   // round-to-nearest-even
  return (short)(u >> 16);
}
__device__ __forceinline__ unsigned pk2(float lo, float hi) {
  return ((unsigned)(unsigned short)f2bf(lo)) | (((unsigned)(unsigned short)f2bf(hi)) << 16);
}

// Load an 8-element bf16 fragment from either bf16 or fp32 source (uniform flag).
__device__ __forceinline__ short8 ldfrag(const void* p, size_t off, int isf32) {
  if (isf32) {
    const float* q = (const float*)p + off;
    f32x4 lo = *(const f32x4*)q;
    f32x4 hi = *(const f32x4*)(q + 4);
    short8 r;
#pragma unroll
    for (int j = 0; j < 4; ++j) { r[j] = f2bf(lo[j]); r[j + 4] = f2bf(hi[j]); }
    return r;
  }
  return *(const short8*)((const short*)p + off);
}
__device__ __forceinline__ float ldbias(const void* b, int i, int isf32) {
  return isf32 ? ((const float*)b)[i] : bf2f(((const short*)b)[i]);
}

// In-kernel dtype probe (per-block, replaces detect_k kernel; validated logic
// from R5/R6). All waves compute identically from W's first 256 words.
__device__ __forceinline__ int detect_f32_inblock(const unsigned* w, int lane) {
  int c = 0;
#pragma unroll
  for (int i = 0; i < 4; ++i) {
    unsigned e = (w[lane * 4 + i] >> 7) & 0xffu;
    c += (e >= 110u && e <= 135u) ? 1 : 0;
  }
#pragma unroll
  for (int off = 32; off; off >>= 1) c += __shfl_xor(c, off);
  return (c < 128) ? 1 : 0;   // bf16 data -> ~256 in-range; fp32 -> ~random
}

#define SZE  ((size_t)2 * T_DIM * C_DIM)

// ---------------------------------------------------------------------------
// Fused QKV GEMM, 128x128 block tile, 4 waves (each 64x64 = 4x4 MFMA tiles),
// BK=32, LDS staged with inline fp32->bf16 convert. m in [0,6144): src=m>>11.
//   q,k -> qp/kp [b,h,t,d] bf16 (TRANS epilogue, verified R5/R6)
//   v   -> vpt   [b,h,d,t] bf16 (NORM epilogue, verified R5/R6)
// LDS rows padded 32->40 shorts (<=2-way conflicts, free per m136).
// ---------------------------------------------------------------------------
#define LDSP 40

__global__ __launch_bounds__(256) void gemm_qkv_k(const void* __restrict__ X0,
                                                  const void* __restrict__ X1,
                                                  const void* __restrict__ X2,
                                                  const void* __restrict__ Wv,
                                                  const void* __restrict__ Bv,
                                                  short* __restrict__ outv)
{
  const int tid  = threadIdx.x;
  const int lane = tid & 63;
  const int wave = tid >> 6;
  const int col16 = lane & 15;
  const int quad  = lane >> 4;
  const int wm = wave & 1;
  const int wn = wave >> 1;

  const int f = detect_f32_inblock((const unsigned*)Wv, lane);
  const int wf = f, xf = f;

  const int m0 = blockIdx.x * 128;
  const int c0 = blockIdx.y * 128;

  const int src = m0 >> 11;               // 0=q 1=k 2=v
  const void* Xv = (src == 0) ? X0 : (src == 1) ? X1 : X2;
  const int arow = m0 & 2047;
  const bool isv = (src == 2);
  short* outb = outv + (size_t)src * SZE;

  __shared__ short As[128 * LDSP];
  __shared__ short Bs[128 * LDSP];

  f32x4 acc[4][4] = {};

  for (int k0 = 0; k0 < KD; k0 += 32) {
    short8 va[2], vb[2];
#pragma unroll
    for (int it = 0; it < 2; ++it) {
      const int cid = tid + 256 * it;     // 512 16B-chunks: 128 rows x 4
      const int row = cid >> 2, c8 = cid & 3;
      va[it] = ldfrag(Xv, (size_t)(arow + row) * KD + k0 + c8 * 8, xf);
      vb[it] = ldfrag(Wv, (size_t)(c0 + row) * KD + k0 + c8 * 8, wf);
    }
#pragma unroll
    for (int it = 0; it < 2; ++it) {
      const int cid = tid + 256 * it;
      const int row = cid >> 2, c8 = cid & 3;
      *(short8*)&As[row * LDSP + c8 * 8] = va[it];
      *(short8*)&Bs[row * LDSP + c8 * 8] = vb[it];
    }
    __syncthreads();

    short8 fx[4], fw[4];
#pragma unroll
    for (int i = 0; i < 4; ++i)
      fx[i] = *(const short8*)&As[(wm * 64 + i * 16 + col16) * LDSP + quad * 8];
#pragma unroll
    for (int j = 0; j < 4; ++j)
      fw[j] = *(const short8*)&Bs[(wn * 64 + j * 16 + col16) * LDSP + quad * 8];

    if (isv) {
#pragma unroll
      for (int i = 0; i < 4; ++i)
#pragma unroll
        for (int j = 0; j < 4; ++j)
          acc[i][j] = __builtin_amdgcn_mfma_f32_16x16x32_bf16(fx[i], fw[j], acc[i][j], 0, 0, 0);
    } else {
#pragma unroll
      for (int i = 0; i < 4; ++i)
#pragma unroll
        for (int j = 0; j < 4; ++j)
          acc[i][j] = __builtin_amdgcn_mfma_f32_16x16x32_bf16(fw[j], fx[i], acc[i][j], 0, 0, 0);
    }
    __syncthreads();
  }

  const int mB = arow + wm * 64;
  const int cB = c0 + wn * 64;
  if (isv) {
    // NORM: col=c(d), rows=m(t) -> vpt [b,h,d,t]   (verified R5 MODE2)
#pragma unroll
    for (int i = 0; i < 4; ++i) {
#pragma unroll
      for (int j = 0; j < 4; ++j) {
        const int c  = cB + j * 16 + col16;
        const int t0 = mB + i * 16 + quad * 4;
        const float bv = ldbias(Bv, c, wf);
        short4v pk;
#pragma unroll
        for (int r = 0; r < 4; ++r) pk[r] = f2bf(acc[i][j][r] + bv);
        const int bb = t0 >> 10, t = t0 & 1023, h = c >> 6, d = c & 63;
        size_t off = (size_t)((bb * H_DIM + h) * D_DIM + d) * T_DIM + t;
        *(short4v*)(outb + off) = pk;
      }
    }
  } else {
    // TRANS: col=m, rows=c -> qp/kp [b,h,t,d]   (verified R5 MODE1)
#pragma unroll
    for (int i = 0; i < 4; ++i) {
#pragma unroll
      for (int j = 0; j < 4; ++j) {
        const int m  = mB + i * 16 + col16;
        const int cb = cB + j * 16 + quad * 4;
        short4v pk;
#pragma unroll
        for (int r = 0; r < 4; ++r) pk[r] = f2bf(acc[i][j][r] + ldbias(Bv, cb + r, wf));
        const int bb = m >> 10, t = m & 1023, h = cb >> 6, d = cb & 63;
        size_t off = ((size_t)(bb * H_DIM + h) << 16) + (size_t)t * D_DIM + d;
        *(short4v*)(outb + off) = pk;
      }
    }
  }
}

// ---------------------------------------------------------------------------
// Final projection GEMM (unchanged structure, verified R6): 64x64 tile,
// out fp32 [m*1024+c]. In-block dtype detect for Wc/bc.
// ---------------------------------------------------------------------------
__global__ __launch_bounds__(256) void gemm_out_k(const short* __restrict__ Xb,
                                                  const void* __restrict__ Wv,
                                                  const void* __restrict__ Bv,
                                                  float* __restrict__ outv)
{
  const int tid  = threadIdx.x;
  const int lane = tid & 63;
  const int wave = tid >> 6;
  const int col16 = lane & 15;
  const int quad  = lane >> 4;
  const int wm = wave & 1;
  const int wn = wave >> 1;

  const int wf = detect_f32_inblock((const unsigned*)Wv, lane);

  const int m0 = blockIdx.x * 64;
  const int c0 = blockIdx.y * 64;

  __shared__ short As[64 * LDSP];
  __shared__ short Bs[64 * LDSP];

  const int srow = tid >> 2;
  const int sc8  = tid & 3;

  f32x4 acc[2][2] = {};

  for (int k0 = 0; k0 < KD; k0 += 32) {
    short8 va = *(const short8*)(Xb + (size_t)(m0 + srow) * KD + k0 + sc8 * 8);
    short8 vb = ldfrag(Wv, (size_t)(c0 + srow) * KD + k0 + sc8 * 8, wf);
    *(short8*)&As[srow * LDSP + sc8 * 8] = va;
    *(short8*)&Bs[srow * LDSP + sc8 * 8] = vb;
    __syncthreads();

    short8 fx[2], fw[2];
#pragma unroll
    for (int i = 0; i < 2; ++i)
      fx[i] = *(const short8*)&As[(wm * 32 + i * 16 + col16) * LDSP + quad * 8];
#pragma unroll
    for (int j = 0; j < 2; ++j)
      fw[j] = *(const short8*)&Bs[(wn * 32 + j * 16 + col16) * LDSP + quad * 8];

#pragma unroll
    for (int i = 0; i < 2; ++i)
#pragma unroll
      for (int j = 0; j < 2; ++j)
        acc[i][j] = __builtin_amdgcn_mfma_f32_16x16x32_bf16(fw[j], fx[i], acc[i][j], 0, 0, 0);
    __syncthreads();
  }

#pragma unroll
  for (int i = 0; i < 2; ++i) {
#pragma unroll
    for (int j = 0; j < 2; ++j) {
      const int m  = m0 + wm * 32 + i * 16 + col16;
      const int cb = c0 + wn * 32 + j * 16 + quad * 4;
      f32x4 pv;
#pragma unroll
      for (int r = 0; r < 4; ++r) pv[r] = acc[i][j][r] + ldbias(Bv, cb + r, wf);
      *(f32x4*)(outv + (size_t)m * C_DIM + cb) = pv;
    }
  }
}

// ---------------------------------------------------------------------------
// Causal flash attention with intra-block key-split (4 waves share one 16-q
// tile, contiguous key ranges, combine via LDS). Inner loop identical to the
// R5/R6-verified transposed-score kernel.
// Grid: (64 qtiles, 32 bh), 256 threads.
// ---------------------------------------------------------------------------
__global__ __launch_bounds__(256) void attn_k2(const short* __restrict__ qp,
                                               const short* __restrict__ kp,
                                               const short* __restrict__ vpt,
                                               short* __restrict__ y)
{
  const int lane = threadIdx.x & 63;
  const int wave = threadIdx.x >> 6;
  const int col  = lane & 15;
  const int quad = lane >> 4;
  const int bh = blockIdx.y;
  const int b = bh >> 4, h = bh & 15;
  const int qt = 63 - (int)blockIdx.x;       // heavy blocks first
  const int q0 = qt * 16;
  const int myq = q0 + col;

  const short* qph = qp  + (size_t)bh * (T_DIM * D_DIM);
  const short* kph = kp  + (size_t)bh * (T_DIM * D_DIM);
  const short* vph = vpt + (size_t)bh * (D_DIM * T_DIM);

  // Key-tile range for this wave (contiguous split of the causal range).
  const int nkt  = (q0 + 47) >> 5;           // tiles of 32 keys covering 0..q0+15
  const int base = nkt >> 2, rem = nkt & 3;
  const int cnt   = base + (wave < rem ? 1 : 0);
  const int start = wave * base + (wave < rem ? wave : rem);

  short8 bQ[2];
#pragma unroll
  for (int kk = 0; kk < 2; ++kk)
    bQ[kk] = *(const short8*)(qph + (size_t)(q0 + col) * D_DIM + kk * 32 + quad * 8);

  f32x4 O[4] = {};
  float m_q = NEG_BIG, l_q = 0.0f;

  const int slA = col + ((quad & 1) * 32);
  const int slB = slA + 16;

  for (int kt = start; kt < start + cnt; ++kt) {
    const int kb = kt * 32;
    f32x4 st[2];
#pragma unroll
    for (int jt = 0; jt < 2; ++jt) {
      f32x4 s = {0.f, 0.f, 0.f, 0.f};
      const short* kbase = kph + (size_t)(kb + jt * 16 + col) * D_DIM + quad * 8;
      short8 aK0 = *(const short8*)(kbase);
      short8 aK1 = *(const short8*)(kbase + 32);
      s = __builtin_amdgcn_mfma_f32_16x16x32_bf16(aK0, bQ[0], s, 0, 0, 0);
      s = __builtin_amdgcn_mfma_f32_16x16x32_bf16(aK1, bQ[1], s, 0, 0, 0);
      st[jt] = s;
    }
    float mnew = m_q;
#pragma unroll
    for (int jt = 0; jt < 2; ++jt) {
#pragma unroll
      for (int r = 0; r < 4; ++r) {
        float sv = st[jt][r] * 0.125f;
        const int key = kb + jt * 16 + quad * 4 + r;
        sv = (key > myq) ? NEG_BIG : sv;
        st[jt][r] = sv;
        mnew = fmaxf(mnew, sv);
      }
    }
    mnew = fmaxf(mnew, __shfl_xor(mnew, 16));
    mnew = fmaxf(mnew, __shfl_xor(mnew, 32));
    const float alpha = __expf(m_q - mnew);
    m_q = mnew;
    float rs = 0.0f;
#pragma unroll
    for (int jt = 0; jt < 2; ++jt) {
#pragma unroll
      for (int r = 0; r < 4; ++r) {
        float p = __expf(st[jt][r] - mnew);
        st[jt][r] = p;
        rs += p;
      }
    }
    rs += __shfl_xor(rs, 16);
    rs += __shfl_xor(rs, 32);
    l_q = l_q * alpha + rs;
#pragma unroll
    for (int dt = 0; dt < 4; ++dt)
#pragma unroll
      for (int r = 0; r < 4; ++r) O[dt][r] *= alpha;

    const int a0 = (int)pk2(st[0][0], st[0][1]);
    const int a1 = (int)pk2(st[0][2], st[0][3]);
    const int b0 = (int)pk2(st[1][0], st[1][1]);
    const int b1 = (int)pk2(st[1][2], st[1][3]);
    const int tA0 = __shfl(a0, slA, 64), tB0 = __shfl(b0, slA, 64);
    const int tA1 = __shfl(a1, slA, 64), tB1 = __shfl(b1, slA, 64);
    const int tA2 = __shfl(a0, slB, 64), tB2 = __shfl(b0, slB, 64);
    const int tA3 = __shfl(a1, slB, 64), tB3 = __shfl(b1, slB, 64);
    union { unsigned u[4]; short8 s8; } uu;
    uu.u[0] = (unsigned)((quad < 2) ? tA0 : tB0);
    uu.u[1] = (unsigned)((quad < 2) ? tA1 : tB1);
    uu.u[2] = (unsigned)((quad < 2) ? tA2 : tB2);
    uu.u[3] = (unsigned)((quad < 2) ? tA3 : tB3);
    const short8 bP32 = uu.s8;

#pragma unroll
    for (int dt = 0; dt < 4; ++dt) {
      short8 aV = *(const short8*)(vph + (size_t)(dt * 16 + col) * T_DIM + kb + quad * 8);
      O[dt] = __builtin_amdgcn_mfma_f32_16x16x32_bf16(aV, bP32, O[dt], 0, 0, 0);
    }
  }

  // ---- combine the 4 per-wave partials via LDS ----
  // Om row = ((w*4+dt)*16 + col), 16 floats (d = quad*4+r within tile dt).
  __shared__ float Om[4 * 4 * 16 * 16];
  __shared__ float Ml[4][2][16];

#pragma unroll
  for (int dt = 0; dt < 4; ++dt)
    *(f32x4*)&Om[(((wave * 4 + dt) * 16) + col) * 16 + quad * 4] = O[dt];
  if (quad == 0) {
    Ml[wave][0][col] = m_q;
    Ml[wave][1][col] = l_q;
  }
  __syncthreads();

  // Each wave outputs d-tile dt == wave.
  float mw[4], lw[4];
#pragma unroll
  for (int w = 0; w < 4; ++w) { mw[w] = Ml[w][0][col]; lw[w] = Ml[w][1][col]; }
  float M = fmaxf(fmaxf(mw[0], mw[1]), fmaxf(mw[2], mw[3]));
  float L = 0.0f;
  f32x4 oacc = {0.f, 0.f, 0.f, 0.f};
#pragma unroll
  for (int w = 0; w < 4; ++w) {
    const float aw = __expf(mw[w] - M);
    L += lw[w] * aw;
    f32x4 ov = *(const f32x4*)&Om[(((w * 4 + wave) * 16) + col) * 16 + quad * 4];
#pragma unroll
    for (int r = 0; r < 4; ++r) oacc[r] += ov[r] * aw;
  }
  const float rl = 1.0f / L;
  const int t = q0 + col;
  const size_t ybase = ((size_t)(b * T_DIM + t)) * C_DIM + h * D_DIM + quad * 4;
  short4v pk;
#pragma unroll
  for (int r = 0; r < 4; ++r) pk[r] = f2bf(oacc[r] * rl);
  *(short4v*)(y + ybase + wave * 16) = pk;
}

// ---------------------------------------------------------------------------
extern "C" void kernel_launch(void* const* d_in, const int* in_sizes, int n_in,
                              void* d_out, int out_size, void* d_ws, size_t ws_size,
                              hipStream_t stream) {
  const void* q = d_in[0];
  const void* k = d_in[1];
  const void* v = d_in[2];
  int wi = (n_in >= 8 && in_sizes[4] == C_DIM * C_DIM) ? 4 : 3;
  const void* Wk = d_in[wi];
  const void* bk = d_in[wi + 1];
  const void* Wc = d_in[wi + 2];
  const void* bc = d_in[wi + 3];

  short* ws  = (short*)d_ws;
  short* qp  = ws;                 // [b,h,t,d] bf16
  short* kp  = ws + SZE;           // [b,h,t,d] bf16
  short* vpt = ws + 2 * SZE;       // [b,h,d,t] bf16
  short* y   = ws + 3 * SZE;       // [b,t,c]   bf16

  dim3 blk(256);
  gemm_qkv_k<<<dim3(48, 8), blk, 0, stream>>>(q, k, v, Wk, bk, qp);
  attn_k2<<<dim3(64, 32), blk, 0, stream>>>(qp, kp, vpt, y);
  gemm_out_k<<<dim3(32, 16), blk, 0, stream>>>(y, Wc, bc, (float*)d_out);
}

// Round 8
// 226.657 us; speedup vs baseline: 1.0246x; 1.0246x over previous
//
#include <hip/hip_runtime.h>

// Problem constants: B=2, T=1024, C=1024, H=16, D=64, K=C=1024.
#define T_DIM 1024
#define C_DIM 1024
#define H_DIM 16
#define D_DIM 64
#define KD    1024

#define NEG_BIG (-1e30f)

typedef short  short8  __attribute__((ext_vector_type(8)));
typedef short  short4v __attribute__((ext_vector_type(4)));
typedef float  f32x4   __attribute__((ext_vector_type(4)));

__device__ __forceinline__ float bf2f(short s) {
  return __uint_as_float(((unsigned)(unsigned short)s) << 16);
}
__device__ __forceinline__ short f2bf(float f) {
  unsigned u = __float_as_uint(f);
  u += 0x7fffu + ((u >> 16) & 1u);   // round-to-nearest-even
  return (short)(u >> 16);
}
__device__ __forceinline__ unsigned pk2(float lo, float hi) {
  return ((unsigned)(unsigned short)f2bf(lo)) | (((unsigned)(unsigned short)f2bf(hi)) << 16);
}

// Load an 8-element bf16 fragment from either bf16 or fp32 source (uniform flag).
__device__ __forceinline__ short8 ldfrag(const void* p, size_t off, int isf32) {
  if (isf32) {
    const float* q = (const float*)p + off;
    f32x4 lo = *(const f32x4*)q;
    f32x4 hi = *(const f32x4*)(q + 4);
    short8 r;
#pragma unroll
    for (int j = 0; j < 4; ++j) { r[j] = f2bf(lo[j]); r[j + 4] = f2bf(hi[j]); }
    return r;
  }
  return *(const short8*)((const short*)p + off);
}
__device__ __forceinline__ float ldbias(const void* b, int i, int isf32) {
  return isf32 ? ((const float*)b)[i] : bf2f(((const short*)b)[i]);
}

// In-kernel dtype probe (validated R6/R7: selected fp32 correctly).
__device__ __forceinline__ int detect_f32_inblock(const unsigned* w, int lane) {
  int c = 0;
#pragma unroll
  for (int i = 0; i < 4; ++i) {
    unsigned e = (w[lane * 4 + i] >> 7) & 0xffu;
    c += (e >= 110u && e <= 135u) ? 1 : 0;
  }
#pragma unroll
  for (int off = 32; off; off >>= 1) c += __shfl_xor(c, off);
  return (c < 128) ? 1 : 0;
}

#define SZE  ((size_t)2 * T_DIM * C_DIM)

// ---------------------------------------------------------------------------
// Chunk-plane LDS layout (conflict-free):
//   tile = 64 rows x 64 k, stored as 8 planes (one per 8-element k-chunk).
//   Plane stride = 257 dwords (64 rows x 4 dw + 1; 257 % 32 == 1).
//   Write (row, c8): addr_dw = c8*257 + row*4 -> bank (c8 + 4*row)%32:
//     staging lanes (row=tid>>3, c8=tid&7) give <=2-way per 16-lane phase (free).
//   Read (row, chunk q): bank (q + 4*row)%32 -> exactly 2-way per phase (free).
// ---------------------------------------------------------------------------
#define PLS 514   // plane stride in shorts (257 dwords)

// ---------------------------------------------------------------------------
// Fused QKV GEMM: 64x64 tile, BK=64, 16 stages, grid (96,16)=1536 blocks (6/CU).
// m in [0,6144): src = m>>11 (q/k/v). out base += src*SZE.
//   q,k -> qp/kp [b,h,t,d] bf16 (TRANS epilogue, verified R5/R6)
//   v   -> vpt   [b,h,d,t] bf16 (NORM epilogue, verified R5/R6)
// ---------------------------------------------------------------------------
__global__ __launch_bounds__(256) void gemm_qkv_k(const void* __restrict__ X0,
                                                  const void* __restrict__ X1,
                                                  const void* __restrict__ X2,
                                                  const void* __restrict__ Wv,
                                                  const void* __restrict__ Bv,
                                                  short* __restrict__ outv)
{
  const int tid  = threadIdx.x;
  const int lane = tid & 63;
  const int wave = tid >> 6;
  const int col16 = lane & 15;
  const int quad  = lane >> 4;
  const int wm = wave & 1;
  const int wn = wave >> 1;

  const int f = detect_f32_inblock((const unsigned*)Wv, lane);
  const int wf = f, xf = f;

  const int m0 = blockIdx.x * 64;
  const int c0 = blockIdx.y * 64;

  const int src = m0 >> 11;               // 0=q 1=k 2=v
  const void* Xv = (src == 0) ? X0 : (src == 1) ? X1 : X2;
  const int arow = m0 & 2047;
  const bool isv = (src == 2);
  short* outb = outv + (size_t)src * SZE;

  __shared__ short As[8 * PLS];
  __shared__ short Bs[8 * PLS];

  const int rA = tid >> 3;                // staging row 0..31 (+32 for 2nd chunk)
  const int c8 = tid & 7;                 // k-chunk 0..7

  f32x4 acc[2][2] = {};

  for (int k0 = 0; k0 < KD; k0 += 64) {
    short8 va0 = ldfrag(Xv, (size_t)(arow + rA) * KD + k0 + c8 * 8, xf);
    short8 va1 = ldfrag(Xv, (size_t)(arow + rA + 32) * KD + k0 + c8 * 8, xf);
    short8 vb0 = ldfrag(Wv, (size_t)(c0 + rA) * KD + k0 + c8 * 8, wf);
    short8 vb1 = ldfrag(Wv, (size_t)(c0 + rA + 32) * KD + k0 + c8 * 8, wf);

    if (k0) __syncthreads();              // previous stage's reads complete
    *(short8*)&As[c8 * PLS + rA * 8]        = va0;
    *(short8*)&As[c8 * PLS + (rA + 32) * 8] = va1;
    *(short8*)&Bs[c8 * PLS + rA * 8]        = vb0;
    *(short8*)&Bs[c8 * PLS + (rA + 32) * 8] = vb1;
    __syncthreads();

#pragma unroll
    for (int kk = 0; kk < 2; ++kk) {
      const int pl = (kk * 4 + quad) * PLS;
      short8 fx[2], fw[2];
#pragma unroll
      for (int i = 0; i < 2; ++i)
        fx[i] = *(const short8*)&As[pl + (wm * 32 + i * 16 + col16) * 8];
#pragma unroll
      for (int j = 0; j < 2; ++j)
        fw[j] = *(const short8*)&Bs[pl + (wn * 32 + j * 16 + col16) * 8];
      if (isv) {
#pragma unroll
        for (int i = 0; i < 2; ++i)
#pragma unroll
          for (int j = 0; j < 2; ++j)
            acc[i][j] = __builtin_amdgcn_mfma_f32_16x16x32_bf16(fx[i], fw[j], acc[i][j], 0, 0, 0);
      } else {
#pragma unroll
        for (int i = 0; i < 2; ++i)
#pragma unroll
          for (int j = 0; j < 2; ++j)
            acc[i][j] = __builtin_amdgcn_mfma_f32_16x16x32_bf16(fw[j], fx[i], acc[i][j], 0, 0, 0);
      }
    }
  }

  if (isv) {
    // NORM: col=c(d), rows=m(t) -> vpt [b,h,d,t]   (verified R5 MODE2)
#pragma unroll
    for (int i = 0; i < 2; ++i) {
#pragma unroll
      for (int j = 0; j < 2; ++j) {
        const int c  = c0 + wn * 32 + j * 16 + col16;
        const int t0 = arow + wm * 32 + i * 16 + quad * 4;
        const float bv = ldbias(Bv, c, wf);
        short4v pk;
#pragma unroll
        for (int r = 0; r < 4; ++r) pk[r] = f2bf(acc[i][j][r] + bv);
        const int bb = t0 >> 10, t = t0 & 1023, h = c >> 6, d = c & 63;
        size_t off = (size_t)((bb * H_DIM + h) * D_DIM + d) * T_DIM + t;
        *(short4v*)(outb + off) = pk;
      }
    }
  } else {
    // TRANS: col=m, rows=c -> qp/kp [b,h,t,d]   (verified R5 MODE1)
#pragma unroll
    for (int i = 0; i < 2; ++i) {
#pragma unroll
      for (int j = 0; j < 2; ++j) {
        const int m  = arow + wm * 32 + i * 16 + col16;
        const int cb = c0 + wn * 32 + j * 16 + quad * 4;
        short4v pk;
#pragma unroll
        for (int r = 0; r < 4; ++r) pk[r] = f2bf(acc[i][j][r] + ldbias(Bv, cb + r, wf));
        const int bb = m >> 10, t = m & 1023, h = cb >> 6, d = cb & 63;
        size_t off = ((size_t)(bb * H_DIM + h) << 16) + (size_t)t * D_DIM + d;
        *(short4v*)(outb + off) = pk;
      }
    }
  }
}

// ---------------------------------------------------------------------------
// Final projection GEMM: same 64x64/BK=64 structure; A = y (bf16, internal),
// out fp32 [m*1024+c] (verified R5/R6). Grid (32,16) = 512 blocks.
// ---------------------------------------------------------------------------
__global__ __launch_bounds__(256) void gemm_out_k(const short* __restrict__ Xb,
                                                  const void* __restrict__ Wv,
                                                  const void* __restrict__ Bv,
                                                  float* __restrict__ outv)
{
  const int tid  = threadIdx.x;
  const int lane = tid & 63;
  const int wave = tid >> 6;
  const int col16 = lane & 15;
  const int quad  = lane >> 4;
  const int wm = wave & 1;
  const int wn = wave >> 1;

  const int wf = detect_f32_inblock((const unsigned*)Wv, lane);

  const int m0 = blockIdx.x * 64;
  const int c0 = blockIdx.y * 64;

  __shared__ short As[8 * PLS];
  __shared__ short Bs[8 * PLS];

  const int rA = tid >> 3;
  const int c8 = tid & 7;

  f32x4 acc[2][2] = {};

  for (int k0 = 0; k0 < KD; k0 += 64) {
    short8 va0 = *(const short8*)(Xb + (size_t)(m0 + rA) * KD + k0 + c8 * 8);
    short8 va1 = *(const short8*)(Xb + (size_t)(m0 + rA + 32) * KD + k0 + c8 * 8);
    short8 vb0 = ldfrag(Wv, (size_t)(c0 + rA) * KD + k0 + c8 * 8, wf);
    short8 vb1 = ldfrag(Wv, (size_t)(c0 + rA + 32) * KD + k0 + c8 * 8, wf);

    if (k0) __syncthreads();
    *(short8*)&As[c8 * PLS + rA * 8]        = va0;
    *(short8*)&As[c8 * PLS + (rA + 32) * 8] = va1;
    *(short8*)&Bs[c8 * PLS + rA * 8]        = vb0;
    *(short8*)&Bs[c8 * PLS + (rA + 32) * 8] = vb1;
    __syncthreads();

#pragma unroll
    for (int kk = 0; kk < 2; ++kk) {
      const int pl = (kk * 4 + quad) * PLS;
      short8 fx[2], fw[2];
#pragma unroll
      for (int i = 0; i < 2; ++i)
        fx[i] = *(const short8*)&As[pl + (wm * 32 + i * 16 + col16) * 8];
#pragma unroll
      for (int j = 0; j < 2; ++j)
        fw[j] = *(const short8*)&Bs[pl + (wn * 32 + j * 16 + col16) * 8];
#pragma unroll
      for (int i = 0; i < 2; ++i)
#pragma unroll
        for (int j = 0; j < 2; ++j)
          acc[i][j] = __builtin_amdgcn_mfma_f32_16x16x32_bf16(fw[j], fx[i], acc[i][j], 0, 0, 0);
    }
  }

#pragma unroll
  for (int i = 0; i < 2; ++i) {
#pragma unroll
    for (int j = 0; j < 2; ++j) {
      const int m  = m0 + wm * 32 + i * 16 + col16;
      const int cb = c0 + wn * 32 + j * 16 + quad * 4;
      f32x4 pv;
#pragma unroll
      for (int r = 0; r < 4; ++r) pv[r] = acc[i][j][r] + ldbias(Bv, cb + r, wf);
      *(f32x4*)(outv + (size_t)m * C_DIM + cb) = pv;
    }
  }
}

// ---------------------------------------------------------------------------
// Causal flash attention, intra-block key-split (verified R7; fast).
// ---------------------------------------------------------------------------
__global__ __launch_bounds__(256) void attn_k2(const short* __restrict__ qp,
                                               const short* __restrict__ kp,
                                               const short* __restrict__ vpt,
                                               short* __restrict__ y)
{
  const int lane = threadIdx.x & 63;
  const int wave = threadIdx.x >> 6;
  const int col  = lane & 15;
  const int quad = lane >> 4;
  const int bh = blockIdx.y;
  const int b = bh >> 4, h = bh & 15;
  const int qt = 63 - (int)blockIdx.x;       // heavy blocks first
  const int q0 = qt * 16;
  const int myq = q0 + col;

  const short* qph = qp  + (size_t)bh * (T_DIM * D_DIM);
  const short* kph = kp  + (size_t)bh * (T_DIM * D_DIM);
  const short* vph = vpt + (size_t)bh * (D_DIM * T_DIM);

  const int nkt  = (q0 + 47) >> 5;
  const int base = nkt >> 2, rem = nkt & 3;
  const int cnt   = base + (wave < rem ? 1 : 0);
  const int start = wave * base + (wave < rem ? wave : rem);

  short8 bQ[2];
#pragma unroll
  for (int kk = 0; kk < 2; ++kk)
    bQ[kk] = *(const short8*)(qph + (size_t)(q0 + col) * D_DIM + kk * 32 + quad * 8);

  f32x4 O[4] = {};
  float m_q = NEG_BIG, l_q = 0.0f;

  const int slA = col + ((quad & 1) * 32);
  const int slB = slA + 16;

  for (int kt = start; kt < start + cnt; ++kt) {
    const int kb = kt * 32;
    f32x4 st[2];
#pragma unroll
    for (int jt = 0; jt < 2; ++jt) {
      f32x4 s = {0.f, 0.f, 0.f, 0.f};
      const short* kbase = kph + (size_t)(kb + jt * 16 + col) * D_DIM + quad * 8;
      short8 aK0 = *(const short8*)(kbase);
      short8 aK1 = *(const short8*)(kbase + 32);
      s = __builtin_amdgcn_mfma_f32_16x16x32_bf16(aK0, bQ[0], s, 0, 0, 0);
      s = __builtin_amdgcn_mfma_f32_16x16x32_bf16(aK1, bQ[1], s, 0, 0, 0);
      st[jt] = s;
    }
    float mnew = m_q;
#pragma unroll
    for (int jt = 0; jt < 2; ++jt) {
#pragma unroll
      for (int r = 0; r < 4; ++r) {
        float sv = st[jt][r] * 0.125f;
        const int key = kb + jt * 16 + quad * 4 + r;
        sv = (key > myq) ? NEG_BIG : sv;
        st[jt][r] = sv;
        mnew = fmaxf(mnew, sv);
      }
    }
    mnew = fmaxf(mnew, __shfl_xor(mnew, 16));
    mnew = fmaxf(mnew, __shfl_xor(mnew, 32));
    const float alpha = __expf(m_q - mnew);
    m_q = mnew;
    float rs = 0.0f;
#pragma unroll
    for (int jt = 0; jt < 2; ++jt) {
#pragma unroll
      for (int r = 0; r < 4; ++r) {
        float p = __expf(st[jt][r] - mnew);
        st[jt][r] = p;
        rs += p;
      }
    }
    rs += __shfl_xor(rs, 16);
    rs += __shfl_xor(rs, 32);
    l_q = l_q * alpha + rs;
#pragma unroll
    for (int dt = 0; dt < 4; ++dt)
#pragma unroll
      for (int r = 0; r < 4; ++r) O[dt][r] *= alpha;

    const int a0 = (int)pk2(st[0][0], st[0][1]);
    const int a1 = (int)pk2(st[0][2], st[0][3]);
    const int b0 = (int)pk2(st[1][0], st[1][1]);
    const int b1 = (int)pk2(st[1][2], st[1][3]);
    const int tA0 = __shfl(a0, slA, 64), tB0 = __shfl(b0, slA, 64);
    const int tA1 = __shfl(a1, slA, 64), tB1 = __shfl(b1, slA, 64);
    const int tA2 = __shfl(a0, slB, 64), tB2 = __shfl(b0, slB, 64);
    const int tA3 = __shfl(a1, slB, 64), tB3 = __shfl(b1, slB, 64);
    union { unsigned u[4]; short8 s8; } uu;
    uu.u[0] = (unsigned)((quad < 2) ? tA0 : tB0);
    uu.u[1] = (unsigned)((quad < 2) ? tA1 : tB1);
    uu.u[2] = (unsigned)((quad < 2) ? tA2 : tB2);
    uu.u[3] = (unsigned)((quad < 2) ? tA3 : tB3);
    const short8 bP32 = uu.s8;

#pragma unroll
    for (int dt = 0; dt < 4; ++dt) {
      short8 aV = *(const short8*)(vph + (size_t)(dt * 16 + col) * T_DIM + kb + quad * 8);
      O[dt] = __builtin_amdgcn_mfma_f32_16x16x32_bf16(aV, bP32, O[dt], 0, 0, 0);
    }
  }

  __shared__ float Om[4 * 4 * 16 * 16];
  __shared__ float Ml[4][2][16];

#pragma unroll
  for (int dt = 0; dt < 4; ++dt)
    *(f32x4*)&Om[(((wave * 4 + dt) * 16) + col) * 16 + quad * 4] = O[dt];
  if (quad == 0) {
    Ml[wave][0][col] = m_q;
    Ml[wave][1][col] = l_q;
  }
  __syncthreads();

  float mw[4], lw[4];
#pragma unroll
  for (int w = 0; w < 4; ++w) { mw[w] = Ml[w][0][col]; lw[w] = Ml[w][1][col]; }
  float M = fmaxf(fmaxf(mw[0], mw[1]), fmaxf(mw[2], mw[3]));
  float L = 0.0f;
  f32x4 oacc = {0.f, 0.f, 0.f, 0.f};
#pragma unroll
  for (int w = 0; w < 4; ++w) {
    const float aw = __expf(mw[w] - M);
    L += lw[w] * aw;
    f32x4 ov = *(const f32x4*)&Om[(((w * 4 + wave) * 16) + col) * 16 + quad * 4];
#pragma unroll
    for (int r = 0; r < 4; ++r) oacc[r] += ov[r] * aw;
  }
  const float rl = 1.0f / L;
  const int t = q0 + col;
  const size_t ybase = ((size_t)(b * T_DIM + t)) * C_DIM + h * D_DIM + quad * 4;
  short4v pk;
#pragma unroll
  for (int r = 0; r < 4; ++r) pk[r] = f2bf(oacc[r] * rl);
  *(short4v*)(y + ybase + wave * 16) = pk;
}

// ---------------------------------------------------------------------------
extern "C" void kernel_launch(void* const* d_in, const int* in_sizes, int n_in,
                              void* d_out, int out_size, void* d_ws, size_t ws_size,
                              hipStream_t stream) {
  const void* q = d_in[0];
  const void* k = d_in[1];
  const void* v = d_in[2];
  int wi = (n_in >= 8 && in_sizes[4] == C_DIM * C_DIM) ? 4 : 3;
  const void* Wk = d_in[wi];
  const void* bk = d_in[wi + 1];
  const void* Wc = d_in[wi + 2];
  const void* bc = d_in[wi + 3];

  short* ws  = (short*)d_ws;
  short* qp  = ws;                 // [b,h,t,d] bf16
  short* kp  = ws + SZE;           // [b,h,t,d] bf16
  short* vpt = ws + 2 * SZE;       // [b,h,d,t] bf16
  short* y   = ws + 3 * SZE;       // [b,t,c]   bf16

  dim3 blk(256);
  gemm_qkv_k<<<dim3(96, 16), blk, 0, stream>>>(q, k, v, Wk, bk, qp);
  attn_k2<<<dim3(64, 32), blk, 0, stream>>>(qp, kp, vpt, y);
  gemm_out_k<<<dim3(32, 16), blk, 0, stream>>>(y, Wc, bc, (float*)d_out);
}